// Round 22
// baseline (201.473 us; speedup 1.0000x reference)
//
#include <hip/hip_runtime.h>
#include <math.h>

#define BB 8
#define LL 2048
#define DD 128
#define HH 4
#define DKK 32
#define DFFF 256

#define NEGMIN (-3.402823466e38f)
#define LOG2E 1.44269504088896f

typedef _Float16 f16;
typedef _Float16 f16x4 __attribute__((ext_vector_type(4)));
typedef _Float16 f16x8 __attribute__((ext_vector_type(8)));
typedef __fp16 h16x2 __attribute__((ext_vector_type(2)));
typedef float f32x4 __attribute__((ext_vector_type(4)));

union PKU { h16x2 h2[2]; f16x4 v; };

// ---------------- merged setup: wconv (blk<1024) | xcvt | maskchk --------
__global__ __launch_bounds__(256) void setup_kernel(
    const float* __restrict__ x, const float* __restrict__ mask,
    const float* __restrict__ Wq, const float* __restrict__ Wk,
    const float* __restrict__ Wv, const float* __restrict__ Wo,
    const float* __restrict__ W1, const float* __restrict__ W2,
    f16* __restrict__ wt, f16* __restrict__ xh, int* __restrict__ flags) {
  const int blk = blockIdx.x;
  const int t = threadIdx.x;
  if (blk < 1024) {
    const int idx = blk * 256 + t;
    const int i = idx >> 17;
    const int r = idx & 131071;
    float val;
    if (r < 49152) {
      const int sel = r / 16384;
      const int rr = r & 16383;
      const int n = rr >> 7, k = rr & 127;
      const float* W = (sel == 0) ? Wq : (sel == 1) ? Wk : Wv;
      val = W[((size_t)(i * 4 + (n >> 5)) * 128 + k) * 32 + (n & 31)];
    } else if (r < 65536) {
      const int r2 = r - 49152;
      const int n = r2 >> 7, k = r2 & 127;
      val = Wo[i * 16384 + k * 128 + n];
    } else if (r < 98304) {
      const int r2 = r - 65536;
      const int n = r2 >> 7, k = r2 & 127;
      val = W1[i * 32768 + k * 256 + n];
    } else {
      const int r2 = r - 98304;
      const int n = r2 >> 8, k = r2 & 255;
      val = W2[i * 32768 + k * 128 + n];
    }
    wt[idx] = (f16)val;
  } else if (blk < 2048) {
    const int i = ((blk - 1024) * 256 + t) * 8;
    float4 v0 = *(const float4*)(x + i);
    float4 v1 = *(const float4*)(x + i + 4);
    f16x8 h;
    h[0] = (f16)v0.x; h[1] = (f16)v0.y; h[2] = (f16)v0.z; h[3] = (f16)v0.w;
    h[4] = (f16)v1.x; h[5] = (f16)v1.y; h[6] = (f16)v1.z; h[7] = (f16)v1.w;
    *(f16x8*)(xh + i) = h;
  } else {
    __shared__ int wok[4];
    const int b = blk - 2048;
    bool ok = true;
    for (int i = t; i < LL; i += 256) ok &= (mask[b * LL + i] == 1.f);
    const bool all_ok = __all(ok);
    if ((t & 63) == 0) wok[t >> 6] = all_ok ? 1 : 0;
    __syncthreads();
    if (t == 0) flags[b] = wok[0] & wok[1] & wok[2] & wok[3];
  }
}

// ---------------- QKV projection via MFMA (layer 0), N-split -------------
__global__ __launch_bounds__(256) void qkv_kernel(
    const f16* __restrict__ xh, const f16* __restrict__ wqkvT,
    f16* __restrict__ qh, f16* __restrict__ kh, f16* __restrict__ vth) {
  const int t = threadIdx.x;
  const int wave = t >> 6, lane = t & 63;
  const int g = lane >> 4, c = lane & 15;
  const int rgrp = wave >> 1, half = wave & 1;
  const int r0g = blockIdx.x * 32 + rgrp * 16;
  const int b4 = (r0g >> 11) * 4;
  const int l0 = r0g & 2047;

  f16x8 a[4];
#pragma unroll
  for (int kt = 0; kt < 4; ++kt)
    a[kt] = *(const f16x8*)(xh + (size_t)(r0g + c) * 128 + kt * 32 + g * 8);

  {
    const f16* wT = wqkvT + half * 16384;
    f16* out = (half == 0) ? qh : kh;
#pragma unroll
    for (int nt = 0; nt < 8; ++nt) {
      f32x4 acc = {0.f, 0.f, 0.f, 0.f};
#pragma unroll
      for (int kt = 0; kt < 4; ++kt) {
        f16x8 bfrag = *(const f16x8*)(wT + (nt * 16 + c) * 128 + kt * 32 + g * 8);
        acc = __builtin_amdgcn_mfma_f32_16x16x32_f16(a[kt], bfrag, acc, 0, 0, 0);
      }
      const int h = nt >> 1, e = (nt & 1) * 16 + c;
#pragma unroll
      for (int r = 0; r < 4; ++r)
        out[((size_t)(b4 + h) * LL + l0 + 4 * g + r) * DKK + e] = (f16)acc[r];
    }
  }
  {
    const f16* wT = wqkvT + 2 * 16384;
#pragma unroll
    for (int nt = 0; nt < 4; ++nt) {
      const int ntg = half * 4 + nt;
      f32x4 acc = {0.f, 0.f, 0.f, 0.f};
#pragma unroll
      for (int kt = 0; kt < 4; ++kt) {
        f16x8 afrag = *(const f16x8*)(wT + (ntg * 16 + c) * 128 + kt * 32 + g * 8);
        acc = __builtin_amdgcn_mfma_f32_16x16x32_f16(afrag, a[kt], acc, 0, 0, 0);
      }
#pragma unroll
      for (int r = 0; r < 4; ++r) {
        const int eg = ntg * 16 + 4 * g + r;
        vth[((size_t)(b4 + (eg >> 5)) * DKK + (eg & 31)) * LL + l0 + c] =
            (f16)acc[r];
      }
    }
  }
}

// ---------------- Flash attention: in-block KV-split x2, 8 waves ---------
// 512 thr: wave = qgrp(0..3) + 4*z. Each wave: 32 q-rows, half the KV
// (16 tiles), barrier-free main loop. One __syncthreads, lane-local merge.
__global__ __launch_bounds__(512, 4) void attn_kernel(
    const f16* __restrict__ qh, const f16* __restrict__ kh,
    const f16* __restrict__ vth, const float* __restrict__ mask,
    const int* __restrict__ bflags, f16* __restrict__ o) {
  __shared__ f16 Vt[8][2][32][72];   // per-wave private, double-buffered
  const int t = threadIdx.x;
  const int wave = t >> 6, lane = t & 63;
  const int g = lane >> 4, c = lane & 15;
  const int qgrp = wave & 3, z = wave >> 2;

  const int flat = blockIdx.x;
  const int xcd = flat & 7, slot = flat >> 3;
  const int bh = xcd * 4 + (slot >> 4);
  const int qb = slot & 15;
  const int b = bh >> 2;
  const int qw = qb * 128 + qgrp * 32;
  const int kv0 = z * (LL / 2);
  const bool nomask_b = (bflags[b] != 0);

  f16x8 qfrag[2];
  float mqv[2] = {1.f, 1.f};
#pragma unroll
  for (int qt = 0; qt < 2; ++qt)
    qfrag[qt] =
        *(const f16x8*)(qh + ((size_t)bh * LL + qw + qt * 16 + c) * DKK + g * 8);
  if (!nomask_b) {
#pragma unroll
    for (int qt = 0; qt < 2; ++qt) mqv[qt] = mask[b * LL + qw + qt * 16 + c];
  }

  f32x4 o4[2][2];
  float m[2], l[2];
#pragma unroll
  for (int qt = 0; qt < 2; ++qt) {
    m[qt] = -3.0e38f; l[qt] = 0.f;
#pragma unroll
    for (int dt = 0; dt < 2; ++dt)
#pragma unroll
      for (int r = 0; r < 4; ++r) o4[qt][dt][r] = 0.f;
  }

  const f16* kp = kh + (size_t)bh * LL * DKK + (size_t)kv0 * DKK +
                  (size_t)c * DKK + g * 8;
  const int vd = lane >> 3, vseg = lane & 7;
  const f16* vp = vth + (size_t)bh * DKK * LL + (size_t)vd * LL + kv0 +
                  vseg * 8;

#define LOADK(DST, KT)                                       \
  {                                                          \
    const f16* _p = kp + (size_t)(KT) * 64 * DKK;            \
    DST[0] = *(const f16x8*)(_p);                            \
    DST[1] = *(const f16x8*)(_p + 16 * DKK);                 \
    DST[2] = *(const f16x8*)(_p + 32 * DKK);                 \
    DST[3] = *(const f16x8*)(_p + 48 * DKK);                 \
  }
#define LOADVREG(DST, KT)                                    \
  {                                                          \
    const f16* _p = vp + (KT) * 64;                          \
    DST[0] = *(const f16x8*)(_p);                            \
    DST[1] = *(const f16x8*)(_p + 8 * LL);                   \
    DST[2] = *(const f16x8*)(_p + 16 * LL);                  \
    DST[3] = *(const f16x8*)(_p + 24 * LL);                  \
  }
#define COMMITV(SRC, BUF)                                    \
  {                                                          \
    *(f16x8*)&Vt[wave][BUF][vd][vseg * 8] = SRC[0];          \
    *(f16x8*)&Vt[wave][BUF][vd + 8][vseg * 8] = SRC[1];      \
    *(f16x8*)&Vt[wave][BUF][vd + 16][vseg * 8] = SRC[2];     \
    *(f16x8*)&Vt[wave][BUF][vd + 24][vseg * 8] = SRC[3];     \
  }

  f16x8 kbA[4], kbB[4], vr[4];

  LOADVREG(vr, 0);
  LOADK(kbA, 0);
  COMMITV(vr, 0);

  for (int kt = 0; kt < 16; ++kt) {
    const int cur = kt & 1;
    if (kt < 15) {
      LOADK(kbB, kt + 1);
      LOADVREG(vr, kt + 1);
    }

    f32x4 st[2][4];
    __builtin_amdgcn_s_setprio(1);
#pragma unroll
    for (int qt = 0; qt < 2; ++qt)
#pragma unroll
      for (int nt = 0; nt < 4; ++nt) {
        f32x4 zz = {0.f, 0.f, 0.f, 0.f};
        st[qt][nt] =
            __builtin_amdgcn_mfma_f32_16x16x32_f16(kbA[nt], qfrag[qt], zz, 0, 0, 0);
      }
    __builtin_amdgcn_s_setprio(0);

    if (!nomask_b) {
      const int k0 = kv0 + kt * 64;
#pragma unroll
      for (int qt = 0; qt < 2; ++qt) {
        const float mq = mqv[qt];
#pragma unroll
        for (int nt = 0; nt < 4; ++nt) {
          float4 mk4 = *(const float4*)(mask + b * LL + k0 + nt * 16 + 4 * g);
          st[qt][nt][0] += (1.f - mq * mk4.x) * NEGMIN;
          st[qt][nt][1] += (1.f - mq * mk4.y) * NEGMIN;
          st[qt][nt][2] += (1.f - mq * mk4.z) * NEGMIN;
          st[qt][nt][3] += (1.f - mq * mk4.w) * NEGMIN;
        }
      }
    }

    f16x4 va[2][4];
#pragma unroll
    for (int dt = 0; dt < 2; ++dt)
#pragma unroll
      for (int nt = 0; nt < 4; ++nt)
        va[dt][nt] = *(const f16x4*)&Vt[wave][cur][dt * 16 + c][nt * 16 + 4 * g];

#pragma unroll
    for (int qt = 0; qt < 2; ++qt) {
      float vml = fmaxf(fmaxf(st[qt][0][0], st[qt][0][1]),
                        fmaxf(st[qt][0][2], st[qt][0][3]));
#pragma unroll
      for (int nt = 1; nt < 4; ++nt)
        vml = fmaxf(vml, fmaxf(fmaxf(st[qt][nt][0], st[qt][nt][1]),
                               fmaxf(st[qt][nt][2], st[qt][nt][3])));

      if (!__all(vml - m[qt] <= 8.f)) {
        float vm = fmaxf(vml, __shfl_xor(vml, 16));
        vm = fmaxf(vm, __shfl_xor(vm, 32));
        const float mn = fmaxf(m[qt], vm);
        const float sc = __builtin_exp2f((m[qt] - mn) * LOG2E);
        l[qt] *= sc;
#pragma unroll
        for (int dt = 0; dt < 2; ++dt)
#pragma unroll
          for (int r = 0; r < 4; ++r) o4[qt][dt][r] *= sc;
        m[qt] = mn;
      }
      const float mn2 = m[qt] * LOG2E;

      float p[4][4];
      float psum = 0.f;
#pragma unroll
      for (int nt = 0; nt < 4; ++nt) {
#pragma unroll
        for (int r = 0; r < 4; ++r) {
          p[nt][r] = __builtin_exp2f(fmaf(st[qt][nt][r], LOG2E, -mn2));
          psum += p[nt][r];
        }
      }
      l[qt] += psum;

      __builtin_amdgcn_s_setprio(1);
#pragma unroll
      for (int nt = 0; nt < 4; ++nt) {
        PKU pk;
        pk.h2[0] = __builtin_amdgcn_cvt_pkrtz(p[nt][0], p[nt][1]);
        pk.h2[1] = __builtin_amdgcn_cvt_pkrtz(p[nt][2], p[nt][3]);
        o4[qt][0] = __builtin_amdgcn_mfma_f32_16x16x16f16(va[0][nt], pk.v,
                                                          o4[qt][0], 0, 0, 0);
        o4[qt][1] = __builtin_amdgcn_mfma_f32_16x16x16f16(va[1][nt], pk.v,
                                                          o4[qt][1], 0, 0, 0);
      }
      __builtin_amdgcn_s_setprio(0);
    }

    if (kt < 15) {
      COMMITV(vr, 1 - cur);
#pragma unroll
      for (int i = 0; i < 4; ++i) kbA[i] = kbB[i];
    }
  }
#undef LOADK
#undef LOADVREG
#undef COMMITV

  // ---- KV-half merge: z=1 waves park partials in their (dead) Vt region --
  if (z == 1) {
    float* pl = (float*)&Vt[wave][0][0][0] + lane * 20;
    *(f32x4*)(pl + 0) = o4[0][0];
    *(f32x4*)(pl + 4) = o4[0][1];
    *(f32x4*)(pl + 8) = o4[1][0];
    *(f32x4*)(pl + 12) = o4[1][1];
    f32x4 mlv;
    mlv[0] = m[0]; mlv[1] = m[1]; mlv[2] = l[0]; mlv[3] = l[1];
    *(f32x4*)(pl + 16) = mlv;
  }
  __syncthreads();
  if (z == 1) return;

  {
    const float* pl = (const float*)&Vt[wave + 4][0][0][0] + lane * 20;
    f32x4 po[2][2];
    po[0][0] = *(const f32x4*)(pl + 0);
    po[0][1] = *(const f32x4*)(pl + 4);
    po[1][0] = *(const f32x4*)(pl + 8);
    po[1][1] = *(const f32x4*)(pl + 12);
    const f32x4 mlv = *(const f32x4*)(pl + 16);

    const int h = bh & 3;
#pragma unroll
    for (int qt = 0; qt < 2; ++qt) {
      const float M = fmaxf(m[qt], mlv[qt]);
      const float w0 = __builtin_exp2f((m[qt] - M) * LOG2E);
      const float w1 = __builtin_exp2f((mlv[qt] - M) * LOG2E);
      float lt = w0 * l[qt] + w1 * mlv[2 + qt];
      lt += __shfl_xor(lt, 16);
      lt += __shfl_xor(lt, 32);
      const float rdiv = 1.f / lt;
      f16* orow = o + ((size_t)b * LL + qw + qt * 16 + c) * DD + h * DKK;
#pragma unroll
      for (int dt = 0; dt < 2; ++dt) {
        f16x4 res;
        res[0] = (f16)((w0 * o4[qt][dt][0] + w1 * po[qt][dt][0]) * rdiv);
        res[1] = (f16)((w0 * o4[qt][dt][1] + w1 * po[qt][dt][1]) * rdiv);
        res[2] = (f16)((w0 * o4[qt][dt][2] + w1 * po[qt][dt][2]) * rdiv);
        res[3] = (f16)((w0 * o4[qt][dt][3] + w1 * po[qt][dt][3]) * rdiv);
        *(f16x4*)(orow + dt * 16 + g * 4) = res;
      }
    }
  }
}

// ---------------- MFMA MLP, N-split (+ fused next-layer QKV) --------------
__global__ __launch_bounds__(256) void mlp_kernel(
    const f16* __restrict__ o, const float* __restrict__ x,
    const f16* __restrict__ WoT, const f16* __restrict__ W1T,
    const f16* __restrict__ W2T, const float* __restrict__ b1,
    const float* __restrict__ b2, float* __restrict__ xout,
    const f16* __restrict__ wqkvT_next,
    f16* __restrict__ qh, f16* __restrict__ kh, f16* __restrict__ vth) {
  __shared__ f16 Xm[32][136];
  __shared__ f16 Fs[32][264];
  const int t = threadIdx.x;
  const int wave = t >> 6, lane = t & 63;
  const int g = lane >> 4, c = lane & 15;
  const int rgrp = wave >> 1, half = wave & 1;
  const int mrow = rgrp * 16;
  const long r0 = (long)blockIdx.x * 32;

  f16x8 a1[4];
#pragma unroll
  for (int kt = 0; kt < 4; ++kt)
    a1[kt] = *(const f16x8*)(o + (r0 + mrow + c) * 128 + kt * 32 + g * 8);

  f32x4 xmreg[4];
#pragma unroll
  for (int nt = 0; nt < 4; ++nt) {
    const int ntg = half * 4 + nt;
    f32x4 acc = {0.f, 0.f, 0.f, 0.f};
#pragma unroll
    for (int kt = 0; kt < 4; ++kt) {
      f16x8 bfrag = *(const f16x8*)(WoT + (ntg * 16 + c) * 128 + kt * 32 + g * 8);
      acc = __builtin_amdgcn_mfma_f32_16x16x32_f16(a1[kt], bfrag, acc, 0, 0, 0);
    }
#pragma unroll
    for (int r = 0; r < 4; ++r) {
      const float xv = x[(r0 + mrow + 4 * g + r) * 128 + ntg * 16 + c];
      acc[r] = (acc[r] + xv) * 0.5f;
      Xm[mrow + 4 * g + r][ntg * 16 + c] = (f16)acc[r];
    }
    xmreg[nt] = acc;
  }
  __syncthreads();

  f16x8 a2[4];
#pragma unroll
  for (int kt = 0; kt < 4; ++kt)
    a2[kt] = *(const f16x8*)&Xm[mrow + c][kt * 32 + g * 8];
#pragma unroll
  for (int nt = 0; nt < 8; ++nt) {
    const int ntg = half * 8 + nt;
    f32x4 acc = {0.f, 0.f, 0.f, 0.f};
#pragma unroll
    for (int kt = 0; kt < 4; ++kt) {
      f16x8 bfrag = *(const f16x8*)(W1T + (ntg * 16 + c) * 128 + kt * 32 + g * 8);
      acc = __builtin_amdgcn_mfma_f32_16x16x32_f16(a2[kt], bfrag, acc, 0, 0, 0);
    }
    const float bj = b1[ntg * 16 + c];
#pragma unroll
    for (int r = 0; r < 4; ++r) {
      const float val = acc[r] + bj;
      Fs[mrow + 4 * g + r][ntg * 16 + c] =
          (f16)(0.5f * val * (1.f + erff(val * 0.70710678118654752f)));
    }
  }
  __syncthreads();

  f16x8 a3[8];
#pragma unroll
  for (int kt = 0; kt < 8; ++kt)
    a3[kt] = *(const f16x8*)&Fs[mrow + c][kt * 32 + g * 8];
#pragma unroll
  for (int nt = 0; nt < 4; ++nt) {
    const int ntg = half * 4 + nt;
    f32x4 acc = {0.f, 0.f, 0.f, 0.f};
#pragma unroll
    for (int kt = 0; kt < 8; ++kt) {
      f16x8 bfrag = *(const f16x8*)(W2T + (ntg * 16 + c) * 256 + kt * 32 + g * 8);
      acc = __builtin_amdgcn_mfma_f32_16x16x32_f16(a3[kt], bfrag, acc, 0, 0, 0);
    }
    const float bj = b2[ntg * 16 + c];
#pragma unroll
    for (int r = 0; r < 4; ++r) {
      const float val = (acc[r] + bj + xmreg[nt][r]) * 0.5f;
      xout[(r0 + mrow + 4 * g + r) * 128 + ntg * 16 + c] = val;
      Xm[mrow + 4 * g + r][ntg * 16 + c] = (f16)val;
    }
  }

  if (wqkvT_next) {
    __syncthreads();
    const int r0g = (int)r0 + mrow;
    const int b4 = (r0g >> 11) * 4;
    const int l0 = r0g & 2047;
    f16x8 a[4];
#pragma unroll
    for (int kt = 0; kt < 4; ++kt)
      a[kt] = *(const f16x8*)&Xm[mrow + c][kt * 32 + g * 8];

    {
      const f16* wT = wqkvT_next + half * 16384;
      f16* out = (half == 0) ? qh : kh;
#pragma unroll
      for (int nt = 0; nt < 8; ++nt) {
        f32x4 acc = {0.f, 0.f, 0.f, 0.f};
#pragma unroll
        for (int kt = 0; kt < 4; ++kt) {
          f16x8 bfrag =
              *(const f16x8*)(wT + (nt * 16 + c) * 128 + kt * 32 + g * 8);
          acc = __builtin_amdgcn_mfma_f32_16x16x32_f16(a[kt], bfrag, acc, 0, 0, 0);
        }
        const int h = nt >> 1, e = (nt & 1) * 16 + c;
#pragma unroll
        for (int r = 0; r < 4; ++r)
          out[((size_t)(b4 + h) * LL + l0 + 4 * g + r) * DKK + e] = (f16)acc[r];
      }
    }
    {
      const f16* wT = wqkvT_next + 2 * 16384;
#pragma unroll
      for (int nt = 0; nt < 4; ++nt) {
        const int ntg = half * 4 + nt;
        f32x4 acc = {0.f, 0.f, 0.f, 0.f};
#pragma unroll
        for (int kt = 0; kt < 4; ++kt) {
          f16x8 afrag =
              *(const f16x8*)(wT + (ntg * 16 + c) * 128 + kt * 32 + g * 8);
          acc = __builtin_amdgcn_mfma_f32_16x16x32_f16(afrag, a[kt], acc, 0, 0, 0);
        }
#pragma unroll
        for (int r = 0; r < 4; ++r) {
          const int eg = ntg * 16 + 4 * g + r;
          vth[((size_t)(b4 + (eg >> 5)) * DKK + (eg & 31)) * LL + l0 + c] =
              (f16)acc[r];
        }
      }
    }
  }
}

extern "C" void kernel_launch(void* const* d_in, const int* in_sizes, int n_in,
                              void* d_out, int out_size, void* d_ws,
                              size_t ws_size, hipStream_t stream) {
  const float* x    = (const float*)d_in[0];
  const float* mask = (const float*)d_in[1];
  const float* Wq   = (const float*)d_in[2];
  const float* Wk   = (const float*)d_in[3];
  const float* Wv   = (const float*)d_in[4];
  const float* Wo   = (const float*)d_in[5];
  const float* W1   = (const float*)d_in[6];
  const float* b1   = (const float*)d_in[7];
  const float* W2   = (const float*)d_in[8];
  const float* b2   = (const float*)d_in[9];

  const size_t SZ = (size_t)BB * LL * DD;
  char* p = (char*)d_ws;
  f16* qh   = (f16*)p;  p += SZ * sizeof(f16);
  f16* kh   = (f16*)p;  p += SZ * sizeof(f16);
  f16* vth  = (f16*)p;  p += SZ * sizeof(f16);
  f16* ob   = (f16*)p;  p += SZ * sizeof(f16);
  f16* xh0  = (f16*)p;  p += SZ * sizeof(f16);
  f16* wt   = (f16*)p;  p += (size_t)262144 * sizeof(f16);
  int* bflags = (int*)p; p += 256;
  float* xA = (float*)p;

  setup_kernel<<<2056, 256, 0, stream>>>(x, mask, Wq, Wk, Wv, Wo, W1, W2,
                                         wt, xh0, bflags);

  for (int i = 0; i < 2; ++i) {
    const float* xin = (i == 0) ? x : xA;
    float* xout = (i == 1) ? (float*)d_out : xA;
    const f16* qkvT_i = wt + (size_t)i * 131072;
    const f16* WoT_i  = wt + (size_t)i * 131072 + 49152;
    const f16* W1T_i  = wt + (size_t)i * 131072 + 65536;
    const f16* W2T_i  = wt + (size_t)i * 131072 + 98304;
    const float* b1_i = b1 + (long)i * DFFF;
    const float* b2_i = b2 + (long)i * DD;
    const f16* qkvT_next = (i == 0) ? (wt + 131072) : nullptr;

    if (i == 0)
      qkv_kernel<<<(BB * LL) / 32, 256, 0, stream>>>(xh0, qkvT_i, qh, kh, vth);
    attn_kernel<<<512, 512, 0, stream>>>(qh, kh, vth, mask, bflags, ob);
    mlp_kernel<<<(BB * LL) / 32, 256, 0, stream>>>(ob, xin, WoT_i, W1T_i, W2T_i,
                                                   b1_i, b2_i, xout,
                                                   qkvT_next, qh, kh, vth);
  }
}

// Round 23
// 197.901 us; speedup vs baseline: 1.0180x; 1.0180x over previous
//
#include <hip/hip_runtime.h>
#include <math.h>

#define BB 8
#define LL 2048
#define DD 128
#define HH 4
#define DKK 32
#define DFFF 256

#define NEGMIN (-3.402823466e38f)
#define LOG2E 1.44269504088896f

typedef _Float16 f16;
typedef _Float16 f16x4 __attribute__((ext_vector_type(4)));
typedef _Float16 f16x8 __attribute__((ext_vector_type(8)));
typedef __fp16 h16x2 __attribute__((ext_vector_type(2)));
typedef float f32x4 __attribute__((ext_vector_type(4)));

union PKU { h16x2 h2[2]; f16x4 v; };

// ---------------- merged setup: wconv (blk<1024) | xcvt | maskchk --------
__global__ __launch_bounds__(256) void setup_kernel(
    const float* __restrict__ x, const float* __restrict__ mask,
    const float* __restrict__ Wq, const float* __restrict__ Wk,
    const float* __restrict__ Wv, const float* __restrict__ Wo,
    const float* __restrict__ W1, const float* __restrict__ W2,
    f16* __restrict__ wt, f16* __restrict__ xh, int* __restrict__ flags) {
  const int blk = blockIdx.x;
  const int t = threadIdx.x;
  if (blk < 1024) {
    const int idx = blk * 256 + t;
    const int i = idx >> 17;
    const int r = idx & 131071;
    float val;
    if (r < 49152) {
      const int sel = r / 16384;
      const int rr = r & 16383;
      const int n = rr >> 7, k = rr & 127;
      const float* W = (sel == 0) ? Wq : (sel == 1) ? Wk : Wv;
      val = W[((size_t)(i * 4 + (n >> 5)) * 128 + k) * 32 + (n & 31)];
    } else if (r < 65536) {
      const int r2 = r - 49152;
      const int n = r2 >> 7, k = r2 & 127;
      val = Wo[i * 16384 + k * 128 + n];
    } else if (r < 98304) {
      const int r2 = r - 65536;
      const int n = r2 >> 7, k = r2 & 127;
      val = W1[i * 32768 + k * 256 + n];
    } else {
      const int r2 = r - 98304;
      const int n = r2 >> 8, k = r2 & 255;
      val = W2[i * 32768 + k * 128 + n];
    }
    wt[idx] = (f16)val;
  } else if (blk < 2048) {
    const int i = ((blk - 1024) * 256 + t) * 8;
    float4 v0 = *(const float4*)(x + i);
    float4 v1 = *(const float4*)(x + i + 4);
    f16x8 h;
    h[0] = (f16)v0.x; h[1] = (f16)v0.y; h[2] = (f16)v0.z; h[3] = (f16)v0.w;
    h[4] = (f16)v1.x; h[5] = (f16)v1.y; h[6] = (f16)v1.z; h[7] = (f16)v1.w;
    *(f16x8*)(xh + i) = h;
  } else {
    __shared__ int wok[4];
    const int b = blk - 2048;
    bool ok = true;
    for (int i = t; i < LL; i += 256) ok &= (mask[b * LL + i] == 1.f);
    const bool all_ok = __all(ok);
    if ((t & 63) == 0) wok[t >> 6] = all_ok ? 1 : 0;
    __syncthreads();
    if (t == 0) flags[b] = wok[0] & wok[1] & wok[2] & wok[3];
  }
}

// ---------------- QKV projection via MFMA (layer 0), N-split -------------
__global__ __launch_bounds__(256) void qkv_kernel(
    const f16* __restrict__ xh, const f16* __restrict__ wqkvT,
    f16* __restrict__ qh, f16* __restrict__ kh, f16* __restrict__ vth) {
  const int t = threadIdx.x;
  const int wave = t >> 6, lane = t & 63;
  const int g = lane >> 4, c = lane & 15;
  const int rgrp = wave >> 1, half = wave & 1;
  const int r0g = blockIdx.x * 32 + rgrp * 16;
  const int b4 = (r0g >> 11) * 4;
  const int l0 = r0g & 2047;

  f16x8 a[4];
#pragma unroll
  for (int kt = 0; kt < 4; ++kt)
    a[kt] = *(const f16x8*)(xh + (size_t)(r0g + c) * 128 + kt * 32 + g * 8);

  {
    const f16* wT = wqkvT + half * 16384;
    f16* out = (half == 0) ? qh : kh;
#pragma unroll
    for (int nt = 0; nt < 8; ++nt) {
      f32x4 acc = {0.f, 0.f, 0.f, 0.f};
#pragma unroll
      for (int kt = 0; kt < 4; ++kt) {
        f16x8 bfrag = *(const f16x8*)(wT + (nt * 16 + c) * 128 + kt * 32 + g * 8);
        acc = __builtin_amdgcn_mfma_f32_16x16x32_f16(a[kt], bfrag, acc, 0, 0, 0);
      }
      const int h = nt >> 1, e = (nt & 1) * 16 + c;
#pragma unroll
      for (int r = 0; r < 4; ++r)
        out[((size_t)(b4 + h) * LL + l0 + 4 * g + r) * DKK + e] = (f16)acc[r];
    }
  }
  {
    const f16* wT = wqkvT + 2 * 16384;
#pragma unroll
    for (int nt = 0; nt < 4; ++nt) {
      const int ntg = half * 4 + nt;
      f32x4 acc = {0.f, 0.f, 0.f, 0.f};
#pragma unroll
      for (int kt = 0; kt < 4; ++kt) {
        f16x8 afrag = *(const f16x8*)(wT + (ntg * 16 + c) * 128 + kt * 32 + g * 8);
        acc = __builtin_amdgcn_mfma_f32_16x16x32_f16(afrag, a[kt], acc, 0, 0, 0);
      }
#pragma unroll
      for (int r = 0; r < 4; ++r) {
        const int eg = ntg * 16 + 4 * g + r;
        vth[((size_t)(b4 + (eg >> 5)) * DKK + (eg & 31)) * LL + l0 + c] =
            (f16)acc[r];
      }
    }
  }
}

// ---------------- Flash attention: barrier-free, shfl-free common path ---
__global__ __launch_bounds__(256, 4) void attn_kernel(
    const f16* __restrict__ qh, const f16* __restrict__ kh,
    const f16* __restrict__ vth, const float* __restrict__ mask,
    const int* __restrict__ bflags, f16* __restrict__ o) {
  __shared__ f16 Vt[4][2][32][72];
  const int t = threadIdx.x;
  const int wave = t >> 6, lane = t & 63;
  const int g = lane >> 4, c = lane & 15;

  const int flat = blockIdx.x;
  const int xcd = flat & 7, slot = flat >> 3;
  const int bh = xcd * 4 + (slot >> 4);
  const int qb = slot & 15;
  const int b = bh >> 2;
  const int qw = qb * 128 + wave * 32;
  const bool nomask_b = (bflags[b] != 0);

  f16x8 qfrag[2];
  float mqv[2] = {1.f, 1.f};
#pragma unroll
  for (int qt = 0; qt < 2; ++qt)
    qfrag[qt] =
        *(const f16x8*)(qh + ((size_t)bh * LL + qw + qt * 16 + c) * DKK + g * 8);
  if (!nomask_b) {
#pragma unroll
    for (int qt = 0; qt < 2; ++qt) mqv[qt] = mask[b * LL + qw + qt * 16 + c];
  }

  f32x4 o4[2][2];
  float m[2], l[2];
#pragma unroll
  for (int qt = 0; qt < 2; ++qt) {
    m[qt] = -3.0e38f; l[qt] = 0.f;
#pragma unroll
    for (int dt = 0; dt < 2; ++dt)
#pragma unroll
      for (int r = 0; r < 4; ++r) o4[qt][dt][r] = 0.f;
  }

  const f16* kp = kh + (size_t)bh * LL * DKK + (size_t)c * DKK + g * 8;
  const int vd = lane >> 3, vseg = lane & 7;
  const f16* vp = vth + (size_t)bh * DKK * LL + (size_t)vd * LL + vseg * 8;

#define LOADK(DST, KT)                                       \
  {                                                          \
    const f16* _p = kp + (size_t)(KT) * 64 * DKK;            \
    DST[0] = *(const f16x8*)(_p);                            \
    DST[1] = *(const f16x8*)(_p + 16 * DKK);                 \
    DST[2] = *(const f16x8*)(_p + 32 * DKK);                 \
    DST[3] = *(const f16x8*)(_p + 48 * DKK);                 \
  }
#define LOADVREG(DST, KT)                                    \
  {                                                          \
    const f16* _p = vp + (KT) * 64;                          \
    DST[0] = *(const f16x8*)(_p);                            \
    DST[1] = *(const f16x8*)(_p + 8 * LL);                   \
    DST[2] = *(const f16x8*)(_p + 16 * LL);                  \
    DST[3] = *(const f16x8*)(_p + 24 * LL);                  \
  }
#define COMMITV(SRC, BUF)                                    \
  {                                                          \
    *(f16x8*)&Vt[wave][BUF][vd][vseg * 8] = SRC[0];          \
    *(f16x8*)&Vt[wave][BUF][vd + 8][vseg * 8] = SRC[1];      \
    *(f16x8*)&Vt[wave][BUF][vd + 16][vseg * 8] = SRC[2];     \
    *(f16x8*)&Vt[wave][BUF][vd + 24][vseg * 8] = SRC[3];     \
  }

  f16x8 kbA[4], kbB[4], vr[4];

  LOADVREG(vr, 0);
  LOADK(kbA, 0);
  COMMITV(vr, 0);

  for (int kt = 0; kt < 32; ++kt) {
    const int cur = kt & 1;
    if (kt < 31) {
      LOADK(kbB, kt + 1);
      LOADVREG(vr, kt + 1);
    }

    f32x4 st[2][4];
    __builtin_amdgcn_s_setprio(1);
#pragma unroll
    for (int qt = 0; qt < 2; ++qt)
#pragma unroll
      for (int nt = 0; nt < 4; ++nt) {
        f32x4 z = {0.f, 0.f, 0.f, 0.f};
        st[qt][nt] =
            __builtin_amdgcn_mfma_f32_16x16x32_f16(kbA[nt], qfrag[qt], z, 0, 0, 0);
      }
    __builtin_amdgcn_s_setprio(0);

    if (!nomask_b) {
      const int k0 = kt * 64;
#pragma unroll
      for (int qt = 0; qt < 2; ++qt) {
        const float mq = mqv[qt];
#pragma unroll
        for (int nt = 0; nt < 4; ++nt) {
          float4 mk4 = *(const float4*)(mask + b * LL + k0 + nt * 16 + 4 * g);
          st[qt][nt][0] += (1.f - mq * mk4.x) * NEGMIN;
          st[qt][nt][1] += (1.f - mq * mk4.y) * NEGMIN;
          st[qt][nt][2] += (1.f - mq * mk4.z) * NEGMIN;
          st[qt][nt][3] += (1.f - mq * mk4.w) * NEGMIN;
        }
      }
    }

    f16x4 va[2][4];
#pragma unroll
    for (int dt = 0; dt < 2; ++dt)
#pragma unroll
      for (int nt = 0; nt < 4; ++nt)
        va[dt][nt] = *(const f16x4*)&Vt[wave][cur][dt * 16 + c][nt * 16 + 4 * g];

#pragma unroll
    for (int qt = 0; qt < 2; ++qt) {
      // per-lane partial max only; full row max deferred to rescale path
      float vml = fmaxf(fmaxf(st[qt][0][0], st[qt][0][1]),
                        fmaxf(st[qt][0][2], st[qt][0][3]));
#pragma unroll
      for (int nt = 1; nt < 4; ++nt)
        vml = fmaxf(vml, fmaxf(fmaxf(st[qt][nt][0], st[qt][nt][1]),
                               fmaxf(st[qt][nt][2], st[qt][nt][3])));

      // defer-max: __all over 64 lanes covers the whole row
      if (!__all(vml - m[qt] <= 8.f)) {
        float vm = fmaxf(vml, __shfl_xor(vml, 16));
        vm = fmaxf(vm, __shfl_xor(vm, 32));
        const float mn = fmaxf(m[qt], vm);
        const float sc = __builtin_exp2f((m[qt] - mn) * LOG2E);
        l[qt] *= sc;
#pragma unroll
        for (int dt = 0; dt < 2; ++dt)
#pragma unroll
          for (int r = 0; r < 4; ++r) o4[qt][dt][r] *= sc;
        m[qt] = mn;
      }
      const float mn2 = m[qt] * LOG2E;

      float p[4][4];
      float psum = 0.f;
#pragma unroll
      for (int nt = 0; nt < 4; ++nt) {
#pragma unroll
        for (int r = 0; r < 4; ++r) {
          p[nt][r] = __builtin_exp2f(fmaf(st[qt][nt][r], LOG2E, -mn2));
          psum += p[nt][r];
        }
      }
      l[qt] += psum;

      __builtin_amdgcn_s_setprio(1);
#pragma unroll
      for (int nt = 0; nt < 4; ++nt) {
        PKU pk;
        pk.h2[0] = __builtin_amdgcn_cvt_pkrtz(p[nt][0], p[nt][1]);
        pk.h2[1] = __builtin_amdgcn_cvt_pkrtz(p[nt][2], p[nt][3]);
        o4[qt][0] = __builtin_amdgcn_mfma_f32_16x16x16f16(va[0][nt], pk.v,
                                                          o4[qt][0], 0, 0, 0);
        o4[qt][1] = __builtin_amdgcn_mfma_f32_16x16x16f16(va[1][nt], pk.v,
                                                          o4[qt][1], 0, 0, 0);
      }
      __builtin_amdgcn_s_setprio(0);
    }

    if (kt < 31) {
      COMMITV(vr, 1 - cur);
#pragma unroll
      for (int i = 0; i < 4; ++i) kbA[i] = kbB[i];
    }
  }
#undef LOADK
#undef LOADVREG
#undef COMMITV

  const int h = bh & 3;
#pragma unroll
  for (int qt = 0; qt < 2; ++qt) {
    float lt = l[qt];
    lt += __shfl_xor(lt, 16);
    lt += __shfl_xor(lt, 32);
    const float rdiv = 1.f / lt;
    f16* orow = o + ((size_t)b * LL + qw + qt * 16 + c) * DD + h * DKK;
#pragma unroll
    for (int dt = 0; dt < 2; ++dt) {
      f16x4 res;
      res[0] = (f16)(o4[qt][dt][0] * rdiv);
      res[1] = (f16)(o4[qt][dt][1] * rdiv);
      res[2] = (f16)(o4[qt][dt][2] * rdiv);
      res[3] = (f16)(o4[qt][dt][3] * rdiv);
      *(f16x4*)(orow + dt * 16 + g * 4) = res;
    }
  }
}

// ---------------- MFMA MLP, N-split (+ fused next-layer QKV) --------------
__global__ __launch_bounds__(256) void mlp_kernel(
    const f16* __restrict__ o, const float* __restrict__ x,
    const f16* __restrict__ WoT, const f16* __restrict__ W1T,
    const f16* __restrict__ W2T, const float* __restrict__ b1,
    const float* __restrict__ b2, float* __restrict__ xout,
    const f16* __restrict__ wqkvT_next,
    f16* __restrict__ qh, f16* __restrict__ kh, f16* __restrict__ vth) {
  __shared__ f16 Xm[32][136];
  __shared__ f16 Fs[32][264];
  const int t = threadIdx.x;
  const int wave = t >> 6, lane = t & 63;
  const int g = lane >> 4, c = lane & 15;
  const int rgrp = wave >> 1, half = wave & 1;
  const int mrow = rgrp * 16;
  const long r0 = (long)blockIdx.x * 32;

  f16x8 a1[4];
#pragma unroll
  for (int kt = 0; kt < 4; ++kt)
    a1[kt] = *(const f16x8*)(o + (r0 + mrow + c) * 128 + kt * 32 + g * 8);

  f32x4 xmreg[4];
#pragma unroll
  for (int nt = 0; nt < 4; ++nt) {
    const int ntg = half * 4 + nt;
    f32x4 acc = {0.f, 0.f, 0.f, 0.f};
#pragma unroll
    for (int kt = 0; kt < 4; ++kt) {
      f16x8 bfrag = *(const f16x8*)(WoT + (ntg * 16 + c) * 128 + kt * 32 + g * 8);
      acc = __builtin_amdgcn_mfma_f32_16x16x32_f16(a1[kt], bfrag, acc, 0, 0, 0);
    }
#pragma unroll
    for (int r = 0; r < 4; ++r) {
      const float xv = x[(r0 + mrow + 4 * g + r) * 128 + ntg * 16 + c];
      acc[r] = (acc[r] + xv) * 0.5f;
      Xm[mrow + 4 * g + r][ntg * 16 + c] = (f16)acc[r];
    }
    xmreg[nt] = acc;
  }
  __syncthreads();

  f16x8 a2[4];
#pragma unroll
  for (int kt = 0; kt < 4; ++kt)
    a2[kt] = *(const f16x8*)&Xm[mrow + c][kt * 32 + g * 8];
#pragma unroll
  for (int nt = 0; nt < 8; ++nt) {
    const int ntg = half * 8 + nt;
    f32x4 acc = {0.f, 0.f, 0.f, 0.f};
#pragma unroll
    for (int kt = 0; kt < 4; ++kt) {
      f16x8 bfrag = *(const f16x8*)(W1T + (ntg * 16 + c) * 128 + kt * 32 + g * 8);
      acc = __builtin_amdgcn_mfma_f32_16x16x32_f16(a2[kt], bfrag, acc, 0, 0, 0);
    }
    const float bj = b1[ntg * 16 + c];
#pragma unroll
    for (int r = 0; r < 4; ++r) {
      const float val = acc[r] + bj;
      Fs[mrow + 4 * g + r][ntg * 16 + c] =
          (f16)(0.5f * val * (1.f + erff(val * 0.70710678118654752f)));
    }
  }
  __syncthreads();

  f16x8 a3[8];
#pragma unroll
  for (int kt = 0; kt < 8; ++kt)
    a3[kt] = *(const f16x8*)&Fs[mrow + c][kt * 32 + g * 8];
#pragma unroll
  for (int nt = 0; nt < 4; ++nt) {
    const int ntg = half * 4 + nt;
    f32x4 acc = {0.f, 0.f, 0.f, 0.f};
#pragma unroll
    for (int kt = 0; kt < 8; ++kt) {
      f16x8 bfrag = *(const f16x8*)(W2T + (ntg * 16 + c) * 256 + kt * 32 + g * 8);
      acc = __builtin_amdgcn_mfma_f32_16x16x32_f16(a3[kt], bfrag, acc, 0, 0, 0);
    }
    const float bj = b2[ntg * 16 + c];
#pragma unroll
    for (int r = 0; r < 4; ++r) {
      const float val = (acc[r] + bj + xmreg[nt][r]) * 0.5f;
      xout[(r0 + mrow + 4 * g + r) * 128 + ntg * 16 + c] = val;
      Xm[mrow + 4 * g + r][ntg * 16 + c] = (f16)val;
    }
  }

  if (wqkvT_next) {
    __syncthreads();
    const int r0g = (int)r0 + mrow;
    const int b4 = (r0g >> 11) * 4;
    const int l0 = r0g & 2047;
    f16x8 a[4];
#pragma unroll
    for (int kt = 0; kt < 4; ++kt)
      a[kt] = *(const f16x8*)&Xm[mrow + c][kt * 32 + g * 8];

    {
      const f16* wT = wqkvT_next + half * 16384;
      f16* out = (half == 0) ? qh : kh;
#pragma unroll
      for (int nt = 0; nt < 8; ++nt) {
        f32x4 acc = {0.f, 0.f, 0.f, 0.f};
#pragma unroll
        for (int kt = 0; kt < 4; ++kt) {
          f16x8 bfrag =
              *(const f16x8*)(wT + (nt * 16 + c) * 128 + kt * 32 + g * 8);
          acc = __builtin_amdgcn_mfma_f32_16x16x32_f16(a[kt], bfrag, acc, 0, 0, 0);
        }
        const int h = nt >> 1, e = (nt & 1) * 16 + c;
#pragma unroll
        for (int r = 0; r < 4; ++r)
          out[((size_t)(b4 + h) * LL + l0 + 4 * g + r) * DKK + e] = (f16)acc[r];
      }
    }
    {
      const f16* wT = wqkvT_next + 2 * 16384;
#pragma unroll
      for (int nt = 0; nt < 4; ++nt) {
        const int ntg = half * 4 + nt;
        f32x4 acc = {0.f, 0.f, 0.f, 0.f};
#pragma unroll
        for (int kt = 0; kt < 4; ++kt) {
          f16x8 afrag =
              *(const f16x8*)(wT + (ntg * 16 + c) * 128 + kt * 32 + g * 8);
          acc = __builtin_amdgcn_mfma_f32_16x16x32_f16(afrag, a[kt], acc, 0, 0, 0);
        }
#pragma unroll
        for (int r = 0; r < 4; ++r) {
          const int eg = ntg * 16 + 4 * g + r;
          vth[((size_t)(b4 + (eg >> 5)) * DKK + (eg & 31)) * LL + l0 + c] =
              (f16)acc[r];
        }
      }
    }
  }
}

extern "C" void kernel_launch(void* const* d_in, const int* in_sizes, int n_in,
                              void* d_out, int out_size, void* d_ws,
                              size_t ws_size, hipStream_t stream) {
  const float* x    = (const float*)d_in[0];
  const float* mask = (const float*)d_in[1];
  const float* Wq   = (const float*)d_in[2];
  const float* Wk   = (const float*)d_in[3];
  const float* Wv   = (const float*)d_in[4];
  const float* Wo   = (const float*)d_in[5];
  const float* W1   = (const float*)d_in[6];
  const float* b1   = (const float*)d_in[7];
  const float* W2   = (const float*)d_in[8];
  const float* b2   = (const float*)d_in[9];

  const size_t SZ = (size_t)BB * LL * DD;
  char* p = (char*)d_ws;
  f16* qh   = (f16*)p;  p += SZ * sizeof(f16);
  f16* kh   = (f16*)p;  p += SZ * sizeof(f16);
  f16* vth  = (f16*)p;  p += SZ * sizeof(f16);
  f16* ob   = (f16*)p;  p += SZ * sizeof(f16);
  f16* xh0  = (f16*)p;  p += SZ * sizeof(f16);
  f16* wt   = (f16*)p;  p += (size_t)262144 * sizeof(f16);
  int* bflags = (int*)p; p += 256;
  float* xA = (float*)p;

  setup_kernel<<<2056, 256, 0, stream>>>(x, mask, Wq, Wk, Wv, Wo, W1, W2,
                                         wt, xh0, bflags);

  for (int i = 0; i < 2; ++i) {
    const float* xin = (i == 0) ? x : xA;
    float* xout = (i == 1) ? (float*)d_out : xA;
    const f16* qkvT_i = wt + (size_t)i * 131072;
    const f16* WoT_i  = wt + (size_t)i * 131072 + 49152;
    const f16* W1T_i  = wt + (size_t)i * 131072 + 65536;
    const f16* W2T_i  = wt + (size_t)i * 131072 + 98304;
    const float* b1_i = b1 + (long)i * DFFF;
    const float* b2_i = b2 + (long)i * DD;
    const f16* qkvT_next = (i == 0) ? (wt + 131072) : nullptr;

    if (i == 0)
      qkv_kernel<<<(BB * LL) / 32, 256, 0, stream>>>(xh0, qkvT_i, qh, kh, vth);
    attn_kernel<<<512, 256, 0, stream>>>(qh, kh, vth, mask, bflags, ob);
    mlp_kernel<<<(BB * LL) / 32, 256, 0, stream>>>(ob, xin, WoT_i, W1T_i, W2T_i,
                                                   b1_i, b2_i, xout,
                                                   qkvT_next, qh, kh, vth);
  }
}